// Round 1
// baseline (239.135 us; speedup 1.0000x reference)
//
#include <hip/hip_runtime.h>
#include <math.h>

#define BATCH   4096
#define NNZ_PER 32
#define FT_IN   49152
#define VIRT    768
#define FT_OUT  1024

// ---------------------------------------------------------------------------
// Transpose fft_w (FT_OUT x VIRT) -> fft_wt (VIRT x FT_OUT)
// ---------------------------------------------------------------------------
__global__ __launch_bounds__(256) void k_tr_fft(const float* __restrict__ fft_w,
                                                float* __restrict__ fft_wt) {
    __shared__ float tile[32][33];
    const int f0 = blockIdx.x * 32;   // VIRT dim
    const int o0 = blockIdx.y * 32;   // FT_OUT dim
    const int tx = threadIdx.x, ty = threadIdx.y;
#pragma unroll
    for (int j = 0; j < 4; ++j)
        tile[ty + 8 * j][tx] = fft_w[(o0 + ty + 8 * j) * VIRT + f0 + tx];
    __syncthreads();
#pragma unroll
    for (int j = 0; j < 4; ++j)
        fft_wt[(f0 + ty + 8 * j) * FT_OUT + o0 + tx] = tile[tx][ty + 8 * j];
}

// ---------------------------------------------------------------------------
// Build combined table W[f][o] = ft_w[o][f] + fft_wt[f % VIRT][o]
// ---------------------------------------------------------------------------
__global__ __launch_bounds__(256) void k_build(const float* __restrict__ ft_w,
                                               const float* __restrict__ fft_wt,
                                               float* __restrict__ W) {
    __shared__ float tile[32][33];
    const int f0 = blockIdx.x * 32;   // FT_IN dim
    const int o0 = blockIdx.y * 32;   // FT_OUT dim
    const int tx = threadIdx.x, ty = threadIdx.y;
#pragma unroll
    for (int j = 0; j < 4; ++j)
        tile[ty + 8 * j][tx] = ft_w[(size_t)(o0 + ty + 8 * j) * FT_IN + f0 + tx];
    __syncthreads();
#pragma unroll
    for (int j = 0; j < 4; ++j) {
        const int f = f0 + ty + 8 * j;
        W[(size_t)f * FT_OUT + o0 + tx] =
            tile[tx][ty + 8 * j] + fft_wt[(f % VIRT) * FT_OUT + o0 + tx];
    }
}

// ---------------------------------------------------------------------------
// Per-row gather + clip + out_w dot + block reduce -> l1[b]
// 256 threads, thread t owns outputs [4t, 4t+4)
// ---------------------------------------------------------------------------
__global__ __launch_bounds__(256) void k_row(const int* __restrict__ stm_idx,
                                             const int* __restrict__ nstm_idx,
                                             const float* __restrict__ values,
                                             const float* __restrict__ W,
                                             const float* __restrict__ ft_b,
                                             const float* __restrict__ fft_b,
                                             const float* __restrict__ out_w,
                                             const float* __restrict__ out_b,
                                             float* __restrict__ l1) {
    const int b = blockIdx.x;
    const int t = threadIdx.x;
    __shared__ int   fs[NNZ_PER];
    __shared__ int   fn[NNZ_PER];
    __shared__ float vv[NNZ_PER];
    if (t < NNZ_PER) {
        fs[t] = stm_idx[2 * (b * NNZ_PER + t) + 1];
        fn[t] = nstm_idx[2 * (b * NNZ_PER + t) + 1];
        vv[t] = values[b * NNZ_PER + t];
    }
    __syncthreads();

    const int o = 4 * t;
    float as0 = 0.f, as1 = 0.f, as2 = 0.f, as3 = 0.f;
    float an0 = 0.f, an1 = 0.f, an2 = 0.f, an3 = 0.f;
#pragma unroll 8
    for (int k = 0; k < NNZ_PER; ++k) {
        const float v = vv[k];
        const float4 ws = *(const float4*)(W + (size_t)fs[k] * FT_OUT + o);
        const float4 wn = *(const float4*)(W + (size_t)fn[k] * FT_OUT + o);
        as0 += v * ws.x; as1 += v * ws.y; as2 += v * ws.z; as3 += v * ws.w;
        an0 += v * wn.x; an1 += v * wn.y; an2 += v * wn.z; an3 += v * wn.w;
    }

    const float4 fb = *(const float4*)(ft_b + o);
    const float4 gb = *(const float4*)(fft_b + o);
    const float b0 = fb.x + gb.x, b1 = fb.y + gb.y, b2 = fb.z + gb.z, b3 = fb.w + gb.w;

    const float hs0 = fminf(fmaxf(as0 + b0, 0.f), 1.f);
    const float hs1 = fminf(fmaxf(as1 + b1, 0.f), 1.f);
    const float hs2 = fminf(fmaxf(as2 + b2, 0.f), 1.f);
    const float hs3 = fminf(fmaxf(as3 + b3, 0.f), 1.f);
    const float hn0 = fminf(fmaxf(an0 + b0, 0.f), 1.f);
    const float hn1 = fminf(fmaxf(an1 + b1, 0.f), 1.f);
    const float hn2 = fminf(fmaxf(an2 + b2, 0.f), 1.f);
    const float hn3 = fminf(fmaxf(an3 + b3, 0.f), 1.f);

    const float4 ows = *(const float4*)(out_w + o);
    const float4 own = *(const float4*)(out_w + FT_OUT + o);
    float partial = hs0 * ows.x + hs1 * ows.y + hs2 * ows.z + hs3 * ows.w +
                    hn0 * own.x + hn1 * own.y + hn2 * own.z + hn3 * own.w;

    // wave64 reduce, then cross-wave via LDS
#pragma unroll
    for (int off = 32; off > 0; off >>= 1)
        partial += __shfl_down(partial, off);
    __shared__ float wsum[4];
    if ((t & 63) == 0) wsum[t >> 6] = partial;
    __syncthreads();
    if (t == 0)
        l1[b] = wsum[0] + wsum[1] + wsum[2] + wsum[3] + out_b[0];
}

// ---------------------------------------------------------------------------
// Fallback (no workspace table): direct strided gather. Slow but correct.
// ---------------------------------------------------------------------------
__global__ __launch_bounds__(256) void k_row_direct(const int* __restrict__ stm_idx,
                                                    const int* __restrict__ nstm_idx,
                                                    const float* __restrict__ values,
                                                    const float* __restrict__ ft_w,
                                                    const float* __restrict__ fft_w,
                                                    const float* __restrict__ ft_b,
                                                    const float* __restrict__ fft_b,
                                                    const float* __restrict__ out_w,
                                                    const float* __restrict__ out_b,
                                                    float* __restrict__ l1) {
    const int b = blockIdx.x;
    const int t = threadIdx.x;
    __shared__ int   fs[NNZ_PER];
    __shared__ int   fn[NNZ_PER];
    __shared__ float vv[NNZ_PER];
    if (t < NNZ_PER) {
        fs[t] = stm_idx[2 * (b * NNZ_PER + t) + 1];
        fn[t] = nstm_idx[2 * (b * NNZ_PER + t) + 1];
        vv[t] = values[b * NNZ_PER + t];
    }
    __syncthreads();

    float partial = 0.f;
    for (int c = 0; c < 4; ++c) {
        const int o = 4 * t + c;
        float as = ft_b[o] + fft_b[o];
        float an = as;
        for (int k = 0; k < NNZ_PER; ++k) {
            const float v = vv[k];
            as += v * (ft_w[(size_t)o * FT_IN + fs[k]] + fft_w[o * VIRT + (fs[k] % VIRT)]);
            an += v * (ft_w[(size_t)o * FT_IN + fn[k]] + fft_w[o * VIRT + (fn[k] % VIRT)]);
        }
        const float hs = fminf(fmaxf(as, 0.f), 1.f);
        const float hn = fminf(fmaxf(an, 0.f), 1.f);
        partial += hs * out_w[o] + hn * out_w[FT_OUT + o];
    }
#pragma unroll
    for (int off = 32; off > 0; off >>= 1)
        partial += __shfl_down(partial, off);
    __shared__ float wsum[4];
    if ((t & 63) == 0) wsum[t >> 6] = partial;
    __syncthreads();
    if (t == 0)
        l1[b] = wsum[0] + wsum[1] + wsum[2] + wsum[3] + out_b[0];
}

// ---------------------------------------------------------------------------
// Final: out[i] = sigmoid(l1[buckets[i] + i]) (BUCKET_COUNT == 1)
// ---------------------------------------------------------------------------
__global__ void k_out(const float* __restrict__ l1, const int* __restrict__ buckets,
                      float* __restrict__ out) {
    const int i = blockIdx.x * blockDim.x + threadIdx.x;
    if (i < BATCH) {
        const int idx = buckets[i] + i;
        const float x = l1[idx];
        out[i] = 1.f / (1.f + expf(-x));
    }
}

extern "C" void kernel_launch(void* const* d_in, const int* in_sizes, int n_in,
                              void* d_out, int out_size, void* d_ws, size_t ws_size,
                              hipStream_t stream) {
    const int*   stm     = (const int*)d_in[0];
    const int*   nstm    = (const int*)d_in[1];
    const float* values  = (const float*)d_in[2];
    const int*   buckets = (const int*)d_in[3];
    const float* ft_w    = (const float*)d_in[4];
    const float* ft_b    = (const float*)d_in[5];
    const float* fft_w   = (const float*)d_in[6];
    const float* fft_b   = (const float*)d_in[7];
    const float* out_w   = (const float*)d_in[8];
    const float* out_b   = (const float*)d_in[9];
    float*       out     = (float*)d_out;

    const size_t W_elems   = (size_t)FT_IN * FT_OUT;
    const size_t fft_elems = (size_t)VIRT * FT_OUT;
    const size_t need      = (W_elems + fft_elems + BATCH) * sizeof(float);

    if (ws_size >= need) {
        float* W      = (float*)d_ws;
        float* fft_wt = W + W_elems;
        float* l1     = fft_wt + fft_elems;
        dim3 blk(32, 8);
        k_tr_fft<<<dim3(VIRT / 32, FT_OUT / 32), blk, 0, stream>>>(fft_w, fft_wt);
        k_build<<<dim3(FT_IN / 32, FT_OUT / 32), blk, 0, stream>>>(ft_w, fft_wt, W);
        k_row<<<BATCH, 256, 0, stream>>>(stm, nstm, values, W, ft_b, fft_b, out_w, out_b, l1);
        k_out<<<BATCH / 256, 256, 0, stream>>>(l1, buckets, out);
    } else {
        float* l1 = (float*)d_ws;
        k_row_direct<<<BATCH, 256, 0, stream>>>(stm, nstm, values, ft_w, fft_w,
                                                ft_b, fft_b, out_w, out_b, l1);
        k_out<<<BATCH / 256, 256, 0, stream>>>(l1, buckets, out);
    }
}

// Round 2
// 148.542 us; speedup vs baseline: 1.6099x; 1.6099x over previous
//
#include <hip/hip_runtime.h>
#include <math.h>

#define BATCH   4096
#define NNZ_PER 32
#define FT_IN   49152
#define VIRT    768
#define FT_OUT  1024

typedef unsigned short ushort_t;
typedef unsigned int   uint_t;

// ---------------------------------------------------------------------------
// Build combined bf16 table Wb[f][o] = bf16(ft_w[o][f] + fft_w[o][f % VIRT])
// Block = (32,8); per block: f-range 32, o-range 64.
// ---------------------------------------------------------------------------
__global__ __launch_bounds__(256) void k_build(const float* __restrict__ ft_w,
                                               const float* __restrict__ fft_w,
                                               ushort_t* __restrict__ Wb) {
    __shared__ float ta[64][33];   // [o][f] ft_w subtile
    __shared__ float tb[64][33];   // [o][f] fft_w subtile
    const int f0  = blockIdx.x * 32;           // FT_IN dim (multiple of 32)
    const int o0  = blockIdx.y * 64;           // FT_OUT dim
    const int fm0 = f0 % VIRT;                 // no wrap: 768 % 32 == 0
    const int tx = threadIdx.x, ty = threadIdx.y;
#pragma unroll
    for (int j = 0; j < 8; ++j) {
        const int oi = ty + 8 * j;
        ta[oi][tx] = ft_w[(size_t)(o0 + oi) * FT_IN + f0 + tx];
        tb[oi][tx] = fft_w[(o0 + oi) * VIRT + fm0 + tx];
    }
    __syncthreads();
#pragma unroll
    for (int j = 0; j < 4; ++j) {
        const int fi = ty + 8 * j;
        const int f  = f0 + fi;
        const float v0 = ta[2 * tx][fi]     + tb[2 * tx][fi];
        const float v1 = ta[2 * tx + 1][fi] + tb[2 * tx + 1][fi];
        // pack 2 bf16 (RNE) into one uint
        union { float f; uint_t u; } c0, c1;
        c0.f = v0; c1.f = v1;
        // round-to-nearest-even bf16
        uint_t r0 = (c0.u + 0x7fff + ((c0.u >> 16) & 1)) >> 16;
        uint_t r1 = (c1.u + 0x7fff + ((c1.u >> 16) & 1)) >> 16;
        uint_t packed = (r0 & 0xffff) | (r1 << 16);
        *(uint_t*)(Wb + (size_t)f * FT_OUT + o0 + 2 * tx) = packed;
    }
}

// ---------------------------------------------------------------------------
// Per-row gather (bf16 table) + clip + out_w dot + block reduce -> l1[b]
// 256 threads: t in [0,128) = stm half, [128,256) = nstm half.
// Each thread owns 8 consecutive outputs (one uint4 = 8 bf16 per gather).
// ---------------------------------------------------------------------------
__global__ __launch_bounds__(256) void k_row(const int* __restrict__ stm_idx,
                                             const int* __restrict__ nstm_idx,
                                             const float* __restrict__ values,
                                             const ushort_t* __restrict__ Wb,
                                             const float* __restrict__ ft_b,
                                             const float* __restrict__ fft_b,
                                             const float* __restrict__ out_w,
                                             const float* __restrict__ out_b,
                                             float* __restrict__ l1) {
    const int b = blockIdx.x;
    const int t = threadIdx.x;
    __shared__ int   fidx[2][NNZ_PER];
    __shared__ float vv[NNZ_PER];
    if (t < NNZ_PER) {
        fidx[0][t] = stm_idx[2 * (b * NNZ_PER + t) + 1];
        fidx[1][t] = nstm_idx[2 * (b * NNZ_PER + t) + 1];
        vv[t] = values[b * NNZ_PER + t];
    }
    __syncthreads();

    const int half = t >> 7;        // wave-uniform (waves 0,1 stm; 2,3 nstm)
    const int tt   = t & 127;
    const int o    = tt * 8;

    float acc[8];
#pragma unroll
    for (int i = 0; i < 8; ++i) acc[i] = 0.f;

#pragma unroll 8
    for (int k = 0; k < NNZ_PER; ++k) {
        const float v = vv[k];
        const size_t row = (size_t)fidx[half][k] * FT_OUT;
        const uint4 w = *((const uint4*)(Wb + row) + tt);
        union { uint_t u; float f; } lo0, hi0, lo1, hi1, lo2, hi2, lo3, hi3;
        lo0.u = w.x << 16; hi0.u = w.x & 0xffff0000u;
        lo1.u = w.y << 16; hi1.u = w.y & 0xffff0000u;
        lo2.u = w.z << 16; hi2.u = w.z & 0xffff0000u;
        lo3.u = w.w << 16; hi3.u = w.w & 0xffff0000u;
        acc[0] += v * lo0.f; acc[1] += v * hi0.f;
        acc[2] += v * lo1.f; acc[3] += v * hi1.f;
        acc[4] += v * lo2.f; acc[5] += v * hi2.f;
        acc[6] += v * lo3.f; acc[7] += v * hi3.f;
    }

    const float4 fb0 = *(const float4*)(ft_b + o);
    const float4 fb1 = *(const float4*)(ft_b + o + 4);
    const float4 gb0 = *(const float4*)(fft_b + o);
    const float4 gb1 = *(const float4*)(fft_b + o + 4);
    const float4 ow0 = *(const float4*)(out_w + half * FT_OUT + o);
    const float4 ow1 = *(const float4*)(out_w + half * FT_OUT + o + 4);

    float bias[8] = { fb0.x + gb0.x, fb0.y + gb0.y, fb0.z + gb0.z, fb0.w + gb0.w,
                      fb1.x + gb1.x, fb1.y + gb1.y, fb1.z + gb1.z, fb1.w + gb1.w };
    float ow[8]   = { ow0.x, ow0.y, ow0.z, ow0.w, ow1.x, ow1.y, ow1.z, ow1.w };

    float partial = 0.f;
#pragma unroll
    for (int i = 0; i < 8; ++i) {
        const float h = fminf(fmaxf(acc[i] + bias[i], 0.f), 1.f);
        partial += h * ow[i];
    }

#pragma unroll
    for (int off = 32; off > 0; off >>= 1)
        partial += __shfl_down(partial, off);
    __shared__ float wsum[4];
    if ((t & 63) == 0) wsum[t >> 6] = partial;
    __syncthreads();
    if (t == 0)
        l1[b] = wsum[0] + wsum[1] + wsum[2] + wsum[3] + out_b[0];
}

// ---------------------------------------------------------------------------
// Fallback (no workspace table): direct strided gather. Slow but correct.
// ---------------------------------------------------------------------------
__global__ __launch_bounds__(256) void k_row_direct(const int* __restrict__ stm_idx,
                                                    const int* __restrict__ nstm_idx,
                                                    const float* __restrict__ values,
                                                    const float* __restrict__ ft_w,
                                                    const float* __restrict__ fft_w,
                                                    const float* __restrict__ ft_b,
                                                    const float* __restrict__ fft_b,
                                                    const float* __restrict__ out_w,
                                                    const float* __restrict__ out_b,
                                                    float* __restrict__ l1) {
    const int b = blockIdx.x;
    const int t = threadIdx.x;
    __shared__ int   fs[NNZ_PER];
    __shared__ int   fn[NNZ_PER];
    __shared__ float vv[NNZ_PER];
    if (t < NNZ_PER) {
        fs[t] = stm_idx[2 * (b * NNZ_PER + t) + 1];
        fn[t] = nstm_idx[2 * (b * NNZ_PER + t) + 1];
        vv[t] = values[b * NNZ_PER + t];
    }
    __syncthreads();

    float partial = 0.f;
    for (int c = 0; c < 4; ++c) {
        const int o = 4 * t + c;
        float as = ft_b[o] + fft_b[o];
        float an = as;
        for (int k = 0; k < NNZ_PER; ++k) {
            const float v = vv[k];
            as += v * (ft_w[(size_t)o * FT_IN + fs[k]] + fft_w[o * VIRT + (fs[k] % VIRT)]);
            an += v * (ft_w[(size_t)o * FT_IN + fn[k]] + fft_w[o * VIRT + (fn[k] % VIRT)]);
        }
        const float hs = fminf(fmaxf(as, 0.f), 1.f);
        const float hn = fminf(fmaxf(an, 0.f), 1.f);
        partial += hs * out_w[o] + hn * out_w[FT_OUT + o];
    }
#pragma unroll
    for (int off = 32; off > 0; off >>= 1)
        partial += __shfl_down(partial, off);
    __shared__ float wsum[4];
    if ((t & 63) == 0) wsum[t >> 6] = partial;
    __syncthreads();
    if (t == 0)
        l1[b] = wsum[0] + wsum[1] + wsum[2] + wsum[3] + out_b[0];
}

// ---------------------------------------------------------------------------
// Final: out[i] = sigmoid(l1[buckets[i] + i]) (BUCKET_COUNT == 1)
// ---------------------------------------------------------------------------
__global__ void k_out(const float* __restrict__ l1, const int* __restrict__ buckets,
                      float* __restrict__ out) {
    const int i = blockIdx.x * blockDim.x + threadIdx.x;
    if (i < BATCH) {
        const int idx = buckets[i] + i;
        const float x = l1[idx];
        out[i] = 1.f / (1.f + expf(-x));
    }
}

extern "C" void kernel_launch(void* const* d_in, const int* in_sizes, int n_in,
                              void* d_out, int out_size, void* d_ws, size_t ws_size,
                              hipStream_t stream) {
    const int*   stm     = (const int*)d_in[0];
    const int*   nstm    = (const int*)d_in[1];
    const float* values  = (const float*)d_in[2];
    const int*   buckets = (const int*)d_in[3];
    const float* ft_w    = (const float*)d_in[4];
    const float* ft_b    = (const float*)d_in[5];
    const float* fft_w   = (const float*)d_in[6];
    const float* fft_b   = (const float*)d_in[7];
    const float* out_w   = (const float*)d_in[8];
    const float* out_b   = (const float*)d_in[9];
    float*       out     = (float*)d_out;

    const size_t W_elems = (size_t)FT_IN * FT_OUT;                 // bf16 elems
    const size_t need    = W_elems * sizeof(ushort_t) + BATCH * sizeof(float);

    if (ws_size >= need) {
        ushort_t* Wb = (ushort_t*)d_ws;
        float*    l1 = (float*)((char*)d_ws + W_elems * sizeof(ushort_t));
        k_build<<<dim3(FT_IN / 32, FT_OUT / 64), dim3(32, 8), 0, stream>>>(ft_w, fft_w, Wb);
        k_row<<<BATCH, 256, 0, stream>>>(stm, nstm, values, Wb, ft_b, fft_b, out_w, out_b, l1);
        k_out<<<BATCH / 256, 256, 0, stream>>>(l1, buckets, out);
    } else {
        float* l1 = (float*)d_ws;
        k_row_direct<<<BATCH, 256, 0, stream>>>(stm, nstm, values, ft_w, fft_w,
                                                ft_b, fft_b, out_w, out_b, l1);
        k_out<<<BATCH / 256, 256, 0, stream>>>(l1, buckets, out);
    }
}

// Round 4
// 140.501 us; speedup vs baseline: 1.7020x; 1.0572x over previous
//
#include <hip/hip_runtime.h>
#include <math.h>

#define BATCH   4096
#define NNZ_PER 32
#define FT_IN   49152
#define VIRT    768
#define FT_OUT  1024

typedef unsigned short ushort_t;
typedef unsigned int   uint_t;

__device__ __forceinline__ uint_t bf16_rne(float x) {
    union { float f; uint_t u; } c; c.f = x;
    return (c.u + 0x7fff + ((c.u >> 16) & 1)) >> 16;
}

// ---------------------------------------------------------------------------
// Build combined bf16 table Wb[f][o] = bf16(ft_w[o][f] + fft_w[o][f % VIRT])
// 64x64 tile per block, 256 threads. float4 loads, uint4 (8x bf16) stores.
// LDS stride 65 -> <=2-way bank conflicts (free) on both phases.
// ---------------------------------------------------------------------------
__global__ __launch_bounds__(256) void k_build(const float* __restrict__ ft_w,
                                               const float* __restrict__ fft_w,
                                               ushort_t* __restrict__ Wb) {
    __shared__ float ta[64][65];   // [o][f] combined subtile
    const int f0  = blockIdx.x * 64;          // FT_IN dim (768 % 64 == 0 -> no wrap)
    const int o0  = blockIdx.y * 64;          // FT_OUT dim
    const int fm0 = f0 % VIRT;
    const int t   = threadIdx.x;
    const int row = t >> 4;                   // 0..15
    const int seg = t & 15;                   // 0..15  (16 B column)

#pragma unroll
    for (int p = 0; p < 4; ++p) {
        const int o = row + p * 16;           // 0..63
        const float4 v = *(const float4*)(ft_w  + (size_t)(o0 + o) * FT_IN + f0  + seg * 4);
        const float4 g = *(const float4*)(fft_w + (size_t)(o0 + o) * VIRT  + fm0 + seg * 4);
        ta[o][seg * 4 + 0] = v.x + g.x;
        ta[o][seg * 4 + 1] = v.y + g.y;
        ta[o][seg * 4 + 2] = v.z + g.z;
        ta[o][seg * 4 + 3] = v.w + g.w;
    }
    __syncthreads();

    const int os = (t & 7) * 8;               // o_local: 0,8,..,56
#pragma unroll
    for (int p = 0; p < 2; ++p) {
        const int fl = (t >> 3) + p * 32;     // f_local: 0..63
        uint_t w[4];
#pragma unroll
        for (int c = 0; c < 4; ++c) {
            const uint_t r0 = bf16_rne(ta[os + 2 * c][fl]);
            const uint_t r1 = bf16_rne(ta[os + 2 * c + 1][fl]);
            w[c] = (r0 & 0xffffu) | (r1 << 16);
        }
        *(uint4*)(Wb + (size_t)(f0 + fl) * FT_OUT + o0 + os) = *(uint4*)w;
    }
}

// ---------------------------------------------------------------------------
// Per-row gather (bf16 table) + clip + out_w dot + block reduce -> l1[b]
// 256 threads: t in [0,128) = stm half, [128,256) = nstm half.
// Each thread owns 8 consecutive outputs (one uint4 = 8 bf16 per gather).
// ---------------------------------------------------------------------------
__global__ __launch_bounds__(256) void k_row(const int* __restrict__ stm_idx,
                                             const int* __restrict__ nstm_idx,
                                             const float* __restrict__ values,
                                             const ushort_t* __restrict__ Wb,
                                             const float* __restrict__ ft_b,
                                             const float* __restrict__ fft_b,
                                             const float* __restrict__ out_w,
                                             const float* __restrict__ out_b,
                                             float* __restrict__ l1) {
    const int b = blockIdx.x;
    const int t = threadIdx.x;
    __shared__ int   fidx[2][NNZ_PER];
    __shared__ float vv[NNZ_PER];
    if (t < NNZ_PER) {
        fidx[0][t] = stm_idx[2 * (b * NNZ_PER + t) + 1];
        fidx[1][t] = nstm_idx[2 * (b * NNZ_PER + t) + 1];
        vv[t] = values[b * NNZ_PER + t];
    }
    __syncthreads();

    const int half = t >> 7;        // wave-uniform (waves 0,1 stm; 2,3 nstm)
    const int tt   = t & 127;
    const int o    = tt * 8;

    float acc[8];
#pragma unroll
    for (int i = 0; i < 8; ++i) acc[i] = 0.f;

#pragma unroll 8
    for (int k = 0; k < NNZ_PER; ++k) {
        const float v = vv[k];
        const size_t row = (size_t)fidx[half][k] * FT_OUT;
        const uint4 w = *((const uint4*)(Wb + row) + tt);
        union { uint_t u; float f; } lo0, hi0, lo1, hi1, lo2, hi2, lo3, hi3;
        lo0.u = w.x << 16; hi0.u = w.x & 0xffff0000u;
        lo1.u = w.y << 16; hi1.u = w.y & 0xffff0000u;
        lo2.u = w.z << 16; hi2.u = w.z & 0xffff0000u;
        lo3.u = w.w << 16; hi3.u = w.w & 0xffff0000u;
        acc[0] += v * lo0.f; acc[1] += v * hi0.f;
        acc[2] += v * lo1.f; acc[3] += v * hi1.f;
        acc[4] += v * lo2.f; acc[5] += v * hi2.f;
        acc[6] += v * lo3.f; acc[7] += v * hi3.f;
    }

    const float4 fb0 = *(const float4*)(ft_b + o);
    const float4 fb1 = *(const float4*)(ft_b + o + 4);
    const float4 gb0 = *(const float4*)(fft_b + o);
    const float4 gb1 = *(const float4*)(fft_b + o + 4);
    const float4 ow0 = *(const float4*)(out_w + half * FT_OUT + o);
    const float4 ow1 = *(const float4*)(out_w + half * FT_OUT + o + 4);

    float bias[8] = { fb0.x + gb0.x, fb0.y + gb0.y, fb0.z + gb0.z, fb0.w + gb0.w,
                      fb1.x + gb1.x, fb1.y + gb1.y, fb1.z + gb1.z, fb1.w + gb1.w };
    float ow[8]   = { ow0.x, ow0.y, ow0.z, ow0.w, ow1.x, ow1.y, ow1.z, ow1.w };

    float partial = 0.f;
#pragma unroll
    for (int i = 0; i < 8; ++i) {
        const float h = fminf(fmaxf(acc[i] + bias[i], 0.f), 1.f);
        partial += h * ow[i];
    }

#pragma unroll
    for (int off = 32; off > 0; off >>= 1)
        partial += __shfl_down(partial, off);
    __shared__ float wsum[4];
    if ((t & 63) == 0) wsum[t >> 6] = partial;
    __syncthreads();
    if (t == 0)
        l1[b] = wsum[0] + wsum[1] + wsum[2] + wsum[3] + out_b[0];
}

// ---------------------------------------------------------------------------
// Fallback (no workspace table): direct strided gather. Slow but correct.
// ---------------------------------------------------------------------------
__global__ __launch_bounds__(256) void k_row_direct(const int* __restrict__ stm_idx,
                                                    const int* __restrict__ nstm_idx,
                                                    const float* __restrict__ values,
                                                    const float* __restrict__ ft_w,
                                                    const float* __restrict__ fft_w,
                                                    const float* __restrict__ ft_b,
                                                    const float* __restrict__ fft_b,
                                                    const float* __restrict__ out_w,
                                                    const float* __restrict__ out_b,
                                                    float* __restrict__ l1) {
    const int b = blockIdx.x;
    const int t = threadIdx.x;
    __shared__ int   fs[NNZ_PER];
    __shared__ int   fn[NNZ_PER];
    __shared__ float vv[NNZ_PER];
    if (t < NNZ_PER) {
        fs[t] = stm_idx[2 * (b * NNZ_PER + t) + 1];
        fn[t] = nstm_idx[2 * (b * NNZ_PER + t) + 1];
        vv[t] = values[b * NNZ_PER + t];
    }
    __syncthreads();

    float partial = 0.f;
    for (int c = 0; c < 4; ++c) {
        const int o = 4 * t + c;
        float as = ft_b[o] + fft_b[o];
        float an = as;
        for (int k = 0; k < NNZ_PER; ++k) {
            const float v = vv[k];
            as += v * (ft_w[(size_t)o * FT_IN + fs[k]] + fft_w[o * VIRT + (fs[k] % VIRT)]);
            an += v * (ft_w[(size_t)o * FT_IN + fn[k]] + fft_w[o * VIRT + (fn[k] % VIRT)]);
        }
        const float hs = fminf(fmaxf(as, 0.f), 1.f);
        const float hn = fminf(fmaxf(an, 0.f), 1.f);
        partial += hs * out_w[o] + hn * out_w[FT_OUT + o];
    }
#pragma unroll
    for (int off = 32; off > 0; off >>= 1)
        partial += __shfl_down(partial, off);
    __shared__ float wsum[4];
    if ((t & 63) == 0) wsum[t >> 6] = partial;
    __syncthreads();
    if (t == 0)
        l1[b] = wsum[0] + wsum[1] + wsum[2] + wsum[3] + out_b[0];
}

// ---------------------------------------------------------------------------
// Final: out[i] = sigmoid(l1[buckets[i] + i]) (BUCKET_COUNT == 1)
// ---------------------------------------------------------------------------
__global__ void k_out(const float* __restrict__ l1, const int* __restrict__ buckets,
                      float* __restrict__ out) {
    const int i = blockIdx.x * blockDim.x + threadIdx.x;
    if (i < BATCH) {
        const int idx = buckets[i] + i;
        const float x = l1[idx];
        out[i] = 1.f / (1.f + expf(-x));
    }
}

extern "C" void kernel_launch(void* const* d_in, const int* in_sizes, int n_in,
                              void* d_out, int out_size, void* d_ws, size_t ws_size,
                              hipStream_t stream) {
    const int*   stm     = (const int*)d_in[0];
    const int*   nstm    = (const int*)d_in[1];
    const float* values  = (const float*)d_in[2];
    const int*   buckets = (const int*)d_in[3];
    const float* ft_w    = (const float*)d_in[4];
    const float* ft_b    = (const float*)d_in[5];
    const float* fft_w   = (const float*)d_in[6];
    const float* fft_b   = (const float*)d_in[7];
    const float* out_w   = (const float*)d_in[8];
    const float* out_b   = (const float*)d_in[9];
    float*       out     = (float*)d_out;

    const size_t W_elems = (size_t)FT_IN * FT_OUT;                 // bf16 elems
    const size_t need    = W_elems * sizeof(ushort_t) + BATCH * sizeof(float);

    if (ws_size >= need) {
        ushort_t* Wb = (ushort_t*)d_ws;
        float*    l1 = (float*)((char*)d_ws + W_elems * sizeof(ushort_t));
        k_build<<<dim3(FT_IN / 64, FT_OUT / 64), 256, 0, stream>>>(ft_w, fft_w, Wb);
        k_row<<<BATCH, 256, 0, stream>>>(stm, nstm, values, Wb, ft_b, fft_b, out_w, out_b, l1);
        k_out<<<BATCH / 256, 256, 0, stream>>>(l1, buckets, out);
    } else {
        float* l1 = (float*)d_ws;
        k_row_direct<<<BATCH, 256, 0, stream>>>(stm, nstm, values, ft_w, fft_w,
                                                ft_b, fft_b, out_w, out_b, l1);
        k_out<<<BATCH / 256, 256, 0, stream>>>(l1, buckets, out);
    }
}

// Round 7
// 135.868 us; speedup vs baseline: 1.7600x; 1.0341x over previous
//
#include <hip/hip_runtime.h>
#include <math.h>

#define BATCH     4096
#define NNZ_PER   32
#define FT_IN     49152
#define VIRT      768
#define FT_OUT    1024
#define ROW_UINTS 384          // 1024 vals * 12 bit / 32
#define NTILES    16           // 1024 / 64 o-tiles

typedef unsigned short ushort_t;
typedef unsigned int   uint_t;

struct u3 { uint_t x, y, z; };

// ---------------------------------------------------------------------------
// Build int12 table. Wq[f] = 384 uints; tile j (64 outputs) = uints [24j,24j+24).
// scale s[f][j] = tilemax/2047; entry stored as rne(val/s)+2048 in 12 bits.
// 64x64 tile per block; tile max computed from LDS.
// ---------------------------------------------------------------------------
__global__ __launch_bounds__(256) void k_build(const float* __restrict__ ft_w,
                                               const float* __restrict__ fft_w,
                                               uint_t* __restrict__ Wq,
                                               float* __restrict__ scales) {
    __shared__ float ta[64][65];      // [o_local][f_local]
    __shared__ float pm[4][64];
    __shared__ float inv_s[64];
    const int f0  = blockIdx.x * 64;  // FT_IN dim (768 % 64 == 0 -> no wrap)
    const int o0  = blockIdx.y * 64;  // FT_OUT dim
    const int fm0 = f0 % VIRT;
    const int t   = threadIdx.x;
    const int row = t >> 4;           // 0..15
    const int seg = t & 15;           // 16 B column

#pragma unroll
    for (int p = 0; p < 4; ++p) {
        const int o = row + p * 16;
        const float4 v = *(const float4*)(ft_w  + (size_t)(o0 + o) * FT_IN + f0  + seg * 4);
        const float4 g = *(const float4*)(fft_w + (size_t)(o0 + o) * VIRT  + fm0 + seg * 4);
        ta[o][seg * 4 + 0] = v.x + g.x;
        ta[o][seg * 4 + 1] = v.y + g.y;
        ta[o][seg * 4 + 2] = v.z + g.z;
        ta[o][seg * 4 + 3] = v.w + g.w;
    }
    __syncthreads();

    // per-feature max over this block's 64 outputs
    {
        const int fl = t & 63, part = t >> 6;
        float m = 0.f;
#pragma unroll
        for (int i = 0; i < 16; ++i)
            m = fmaxf(m, fabsf(ta[part * 16 + i][fl]));
        pm[part][fl] = m;
    }
    __syncthreads();
    if (t < 64) {
        const float mx = fmaxf(fmaxf(pm[0][t], pm[1][t]), fmaxf(pm[2][t], pm[3][t]));
        inv_s[t] = (mx > 0.f) ? 2047.0f / mx : 0.f;
        scales[(size_t)(f0 + t) * NTILES + (o0 >> 6)] = mx * (1.0f / 2047.0f);
    }
    __syncthreads();

    // pack 512 groups of 8 outputs; each thread does 2 groups
#pragma unroll
    for (int p = 0; p < 2; ++p) {
        const int gi = t + p * 256;
        const int fl = gi >> 3;       // 0..63
        const int g  = gi & 7;        // 8-output group within tile
        const float inv = inv_s[fl];
        int q[8];
#pragma unroll
        for (int j = 0; j < 8; ++j) {
            int qi = __float2int_rn(ta[g * 8 + j][fl] * inv);
            qi = max(-2047, min(2047, qi));
            q[j] = qi + 2048;         // 12-bit unsigned
        }
        const uint_t u0 = (uint_t)q[0] | ((uint_t)q[1] << 12) | (((uint_t)q[2] & 0xFFu) << 24);
        const uint_t u1 = ((uint_t)q[2] >> 8) | ((uint_t)q[3] << 4) |
                          ((uint_t)q[4] << 16) | (((uint_t)q[5] & 0xFu) << 28);
        const uint_t u2 = ((uint_t)q[5] >> 4) | ((uint_t)q[6] << 8) | ((uint_t)q[7] << 20);
        uint_t* dst = Wq + (size_t)(f0 + fl) * ROW_UINTS + (o0 >> 6) * 24 + g * 3;
        dst[0] = u0; dst[1] = u1; dst[2] = u2;
    }
}

// ---------------------------------------------------------------------------
// Per-row gather (int12 table) + clip + out_w dot + block reduce -> l1[b]
// 256 threads: [0,128) stm, [128,256) nstm; thread owns 8 outputs (12 B/gather).
// ---------------------------------------------------------------------------
__global__ __launch_bounds__(256) void k_row(const int* __restrict__ stm_idx,
                                             const int* __restrict__ nstm_idx,
                                             const float* __restrict__ values,
                                             const uint_t* __restrict__ Wq,
                                             const float* __restrict__ scales,
                                             const float* __restrict__ ft_b,
                                             const float* __restrict__ fft_b,
                                             const float* __restrict__ out_w,
                                             const float* __restrict__ out_b,
                                             float* __restrict__ l1) {
    const int b = blockIdx.x;
    const int t = threadIdx.x;
    __shared__ int   fidx[2][NNZ_PER];
    __shared__ float vv[NNZ_PER];
    __shared__ float scs[2][NNZ_PER][NTILES];   // 4 KB
    if (t < NNZ_PER) {
        fidx[0][t] = stm_idx[2 * (b * NNZ_PER + t) + 1];
        fidx[1][t] = nstm_idx[2 * (b * NNZ_PER + t) + 1];
        vv[t] = values[b * NNZ_PER + t];
    }
    __syncthreads();
#pragma unroll
    for (int p = 0; p < 4; ++p) {
        const int idx = t + p * 256;            // 0..1023 over [2][32][16]
        const int h = idx >> 9, k = (idx >> 4) & 31, j = idx & 15;
        scs[h][k][j] = scales[(size_t)fidx[h][k] * NTILES + j];
    }
    __syncthreads();

    const int half = t >> 7;        // wave-uniform
    const int tt   = t & 127;
    const int o    = tt * 8;
    const int jt   = tt >> 3;       // o-tile of this thread's outputs

    float acc[8];
#pragma unroll
    for (int i = 0; i < 8; ++i) acc[i] = 0.f;

#pragma unroll 8
    for (int k = 0; k < NNZ_PER; ++k) {
        const float c = vv[k] * scs[half][k][jt];
        const u3 w = *(const u3*)(Wq + (size_t)fidx[half][k] * ROW_UINTS + tt * 3);
        const uint_t u0 = w.x, u1 = w.y, u2 = w.z;
        const int q0 = (int)( u0         & 0xFFFu);
        const int q1 = (int)((u0 >> 12)  & 0xFFFu);
        const int q2 = (int)((u0 >> 24) | ((u1 & 0xFu) << 8));
        const int q3 = (int)((u1 >> 4)   & 0xFFFu);
        const int q4 = (int)((u1 >> 16)  & 0xFFFu);
        const int q5 = (int)((u1 >> 28) | ((u2 & 0xFFu) << 4));
        const int q6 = (int)((u2 >> 8)   & 0xFFFu);
        const int q7 = (int)( u2 >> 20);
        acc[0] += c * (float)(q0 - 2048);
        acc[1] += c * (float)(q1 - 2048);
        acc[2] += c * (float)(q2 - 2048);
        acc[3] += c * (float)(q3 - 2048);
        acc[4] += c * (float)(q4 - 2048);
        acc[5] += c * (float)(q5 - 2048);
        acc[6] += c * (float)(q6 - 2048);
        acc[7] += c * (float)(q7 - 2048);
    }

    const float4 fb0 = *(const float4*)(ft_b + o);
    const float4 fb1 = *(const float4*)(ft_b + o + 4);
    const float4 gb0 = *(const float4*)(fft_b + o);
    const float4 gb1 = *(const float4*)(fft_b + o + 4);
    const float4 ow0 = *(const float4*)(out_w + half * FT_OUT + o);
    const float4 ow1 = *(const float4*)(out_w + half * FT_OUT + o + 4);

    float bias[8] = { fb0.x + gb0.x, fb0.y + gb0.y, fb0.z + gb0.z, fb0.w + gb0.w,
                      fb1.x + gb1.x, fb1.y + gb1.y, fb1.z + gb1.z, fb1.w + gb1.w };
    float ow[8]   = { ow0.x, ow0.y, ow0.z, ow0.w, ow1.x, ow1.y, ow1.z, ow1.w };

    float partial = 0.f;
#pragma unroll
    for (int i = 0; i < 8; ++i) {
        const float h = fminf(fmaxf(acc[i] + bias[i], 0.f), 1.f);
        partial += h * ow[i];
    }

#pragma unroll
    for (int off = 32; off > 0; off >>= 1)
        partial += __shfl_down(partial, off);
    __shared__ float wsum[4];
    if ((t & 63) == 0) wsum[t >> 6] = partial;
    __syncthreads();
    if (t == 0)
        l1[b] = wsum[0] + wsum[1] + wsum[2] + wsum[3] + out_b[0];
}

// ---------------------------------------------------------------------------
// Fallback (no workspace table): direct strided gather. Slow but correct.
// ---------------------------------------------------------------------------
__global__ __launch_bounds__(256) void k_row_direct(const int* __restrict__ stm_idx,
                                                    const int* __restrict__ nstm_idx,
                                                    const float* __restrict__ values,
                                                    const float* __restrict__ ft_w,
                                                    const float* __restrict__ fft_w,
                                                    const float* __restrict__ ft_b,
                                                    const float* __restrict__ fft_b,
                                                    const float* __restrict__ out_w,
                                                    const float* __restrict__ out_b,
                                                    float* __restrict__ l1) {
    const int b = blockIdx.x;
    const int t = threadIdx.x;
    __shared__ int   fs[NNZ_PER];
    __shared__ int   fn[NNZ_PER];
    __shared__ float vv[NNZ_PER];
    if (t < NNZ_PER) {
        fs[t] = stm_idx[2 * (b * NNZ_PER + t) + 1];
        fn[t] = nstm_idx[2 * (b * NNZ_PER + t) + 1];
        vv[t] = values[b * NNZ_PER + t];
    }
    __syncthreads();

    float partial = 0.f;
    for (int c = 0; c < 4; ++c) {
        const int o = 4 * t + c;
        float as = ft_b[o] + fft_b[o];
        float an = as;
        for (int k = 0; k < NNZ_PER; ++k) {
            const float v = vv[k];
            as += v * (ft_w[(size_t)o * FT_IN + fs[k]] + fft_w[o * VIRT + (fs[k] % VIRT)]);
            an += v * (ft_w[(size_t)o * FT_IN + fn[k]] + fft_w[o * VIRT + (fn[k] % VIRT)]);
        }
        const float hs = fminf(fmaxf(as, 0.f), 1.f);
        const float hn = fminf(fmaxf(an, 0.f), 1.f);
        partial += hs * out_w[o] + hn * out_w[FT_OUT + o];
    }
#pragma unroll
    for (int off = 32; off > 0; off >>= 1)
        partial += __shfl_down(partial, off);
    __shared__ float wsum[4];
    if ((t & 63) == 0) wsum[t >> 6] = partial;
    __syncthreads();
    if (t == 0)
        l1[b] = wsum[0] + wsum[1] + wsum[2] + wsum[3] + out_b[0];
}

// ---------------------------------------------------------------------------
// Final: out[i] = sigmoid(l1[buckets[i] + i]) (BUCKET_COUNT == 1)
// ---------------------------------------------------------------------------
__global__ void k_out(const float* __restrict__ l1, const int* __restrict__ buckets,
                      float* __restrict__ out) {
    const int i = blockIdx.x * blockDim.x + threadIdx.x;
    if (i < BATCH) {
        const int idx = buckets[i] + i;
        const float x = l1[idx];
        out[i] = 1.f / (1.f + expf(-x));
    }
}

extern "C" void kernel_launch(void* const* d_in, const int* in_sizes, int n_in,
                              void* d_out, int out_size, void* d_ws, size_t ws_size,
                              hipStream_t stream) {
    const int*   stm     = (const int*)d_in[0];
    const int*   nstm    = (const int*)d_in[1];
    const float* values  = (const float*)d_in[2];
    const int*   buckets = (const int*)d_in[3];
    const float* ft_w    = (const float*)d_in[4];
    const float* ft_b    = (const float*)d_in[5];
    const float* fft_w   = (const float*)d_in[6];
    const float* fft_b   = (const float*)d_in[7];
    const float* out_w   = (const float*)d_in[8];
    const float* out_b   = (const float*)d_in[9];
    float*       out     = (float*)d_out;

    const size_t Wq_bytes = (size_t)FT_IN * ROW_UINTS * sizeof(uint_t);   // 75.5 MB
    const size_t sc_bytes = (size_t)FT_IN * NTILES * sizeof(float);       // 3 MB
    const size_t need     = Wq_bytes + sc_bytes + BATCH * sizeof(float);

    if (ws_size >= need) {
        uint_t* Wq     = (uint_t*)d_ws;
        float*  scales = (float*)((char*)d_ws + Wq_bytes);
        float*  l1     = (float*)((char*)d_ws + Wq_bytes + sc_bytes);
        k_build<<<dim3(FT_IN / 64, FT_OUT / 64), 256, 0, stream>>>(ft_w, fft_w, Wq, scales);
        k_row<<<BATCH, 256, 0, stream>>>(stm, nstm, values, Wq, scales,
                                         ft_b, fft_b, out_w, out_b, l1);
        k_out<<<BATCH / 256, 256, 0, stream>>>(l1, buckets, out);
    } else {
        float* l1 = (float*)d_ws;
        k_row_direct<<<BATCH, 256, 0, stream>>>(stm, nstm, values, ft_w, fft_w,
                                                ft_b, fft_b, out_w, out_b, l1);
        k_out<<<BATCH / 256, 256, 0, stream>>>(l1, buckets, out);
    }
}